// Round 1
// baseline (218.226 us; speedup 1.0000x reference)
//
#include <hip/hip_runtime.h>

// out[n,c,h,w]:
//   c in [0,64)    : x[n, c+64, (h-1)&63, w]
//   c in [64,128)  : x[n, c-64, (h+1)&63, w]
//   c in [128,192) : x[n, c+64, h, (w-1)&63]
//   c in [192,256) : x[n, c-64, h, (w+1)&63]
//
// Layout constants: N=32, C=256, H=64, W=64.
// One thread per float4 of output. tid bits: [0:3]=w4, [4:9]=h, [10:17]=c, [18:]=n.
// out flat index == 4*tid (coalesced float4 store).

__global__ __launch_bounds__(256) void swap_kernel(const float* __restrict__ x,
                                                   float* __restrict__ out) {
    const int tid = blockIdx.x * blockDim.x + threadIdx.x;
    const int w0 = (tid & 15) << 2;        // 0,4,...,60
    const int h  = (tid >> 4) & 63;
    const int c  = (tid >> 10) & 255;
    const int n  = tid >> 18;
    const int g  = c >> 6;                 // wave-uniform (c constant per wave)

    const long nbase = (long)n << 20;      // n * 256 * 4096
    float4 r;

    if (g == 0) {
        // read row (h-1)&63 of channel c+64, aligned float4
        const float* src = x + nbase + ((long)(c + 64) << 12) + (long)(((h - 1) & 63) << 6) + w0;
        r = *reinterpret_cast<const float4*>(src);
    } else if (g == 1) {
        const float* src = x + nbase + ((long)(c - 64) << 12) + (long)(((h + 1) & 63) << 6) + w0;
        r = *reinterpret_cast<const float4*>(src);
    } else if (g == 2) {
        // out[w] = row[(w-1)&63]: need row[w0-1 .. w0+2]
        const float* row = x + nbase + ((long)(c + 64) << 12) + (long)(h << 6);
        float4 f = *reinterpret_cast<const float4*>(row + w0);
        float  p = row[(w0 - 1) & 63];
        r = make_float4(p, f.x, f.y, f.z);
    } else {
        // out[w] = row[(w+1)&63]: need row[w0+1 .. w0+4]
        const float* row = x + nbase + ((long)(c - 64) << 12) + (long)(h << 6);
        float4 f  = *reinterpret_cast<const float4*>(row + w0);
        float  nx = row[(w0 + 4) & 63];
        r = make_float4(f.y, f.z, f.w, nx);
    }

    *reinterpret_cast<float4*>(out + ((long)tid << 2)) = r;
}

extern "C" void kernel_launch(void* const* d_in, const int* in_sizes, int n_in,
                              void* d_out, int out_size, void* d_ws, size_t ws_size,
                              hipStream_t stream) {
    const float* x   = (const float*)d_in[0];
    float*       out = (float*)d_out;
    // total float4s = 32*256*64*16 = 8,388,608 -> 32768 blocks of 256
    const int total_vec4 = (32 * 256 * 64 * 64) / 4;
    const int block = 256;
    const int grid  = total_vec4 / block;  // 32768
    swap_kernel<<<grid, block, 0, stream>>>(x, out);
}